// Round 6
// baseline (471.035 us; speedup 1.0000x reference)
//
#include <hip/hip_runtime.h>
#include <hip/hip_bf16.h>
#include <stdint.h>

// Problem constants (IMAGE_SIZES is compile-time constant in the reference)
#define K_DIM 4096          // D * MERGE^2
#define N_DIM 1024          // D
#define M_TOT 11955         // total merged blocks

#define BM 128
#define BN 128
#define BK 64
#define NWG_M 94            // ceil(11955/128)
#define NWG 752             // 94 * 8, divisible by 8 XCDs

// Per-image tables: h = H/14, w = W/14; wm = w/2
__constant__ int c_wm[6]     = {44, 55, 45, 55, 32, 55};
__constant__ int c_w[6]      = {88, 110, 90, 110, 64, 110};
__constant__ int c_tokoff[6] = {0, 9680, 18480, 24240, 36340, 42100};
__constant__ int c_blkoff[6] = {0, 2420, 4620, 6060, 9085, 10525};

typedef __attribute__((ext_vector_type(8))) short bf16x8;
typedef __attribute__((ext_vector_type(4))) float f32x4;

// ---------------------------------------------------------------------------
// Weight fp32 -> bf16 with K-permutation k' = seg*1024 + d where original
// k = 4d + seg (seg = 2*kh + kw). Wp[n, seg*1024+d] = W[n, 4d+seg].
// ---------------------------------------------------------------------------
__global__ __launch_bounds__(256) void wperm_cvt(
    const float* __restrict__ src, __hip_bfloat16* __restrict__ dst)
{
    const int n = blockIdx.x >> 1;
    const int t = (blockIdx.x & 1) * 256 + threadIdx.x;   // 0..511
    const float* row = src + (size_t)n * K_DIM + t * 8;
    float4 a = *(const float4*)row;        // k = 8t..8t+3  (d = 2t)
    float4 b = *(const float4*)(row + 4);  // k = 8t+4..8t+7 (d = 2t+1)
    const float va[8] = {a.x, a.y, a.z, a.w, b.x, b.y, b.z, b.w};
    __hip_bfloat16* drow = dst + (size_t)n * K_DIM + 2 * t;
#pragma unroll
    for (int seg = 0; seg < 4; ++seg) {
        __hip_bfloat162 h = __float22bfloat162_rn(
            make_float2(va[seg], va[4 + seg]));
        *(__hip_bfloat162*)(drow + seg * 1024) = h;
    }
}

// ---------------------------------------------------------------------------
// Unfold + cvt: Am[m, seg*1024+d] = bf16(feat[tok(m,seg)*1024 + d]).
// One block per merged row: 4x 4KB contiguous reads, one 8KB contiguous
// write. After this the GEMM is a plain dense [M x 4096] @ [1024 x 4096]^T.
// ---------------------------------------------------------------------------
__global__ __launch_bounds__(256) void unfold_cvt(
    const float* __restrict__ feat, __hip_bfloat16* __restrict__ Am)
{
    const int m = blockIdx.x;            // 0..M_TOT-1
    const int t = threadIdx.x;           // 0..255
    const int seg = t >> 6;              // 0..3
    const int d0 = (t & 63) * 16;        // 0..1008
    int img = 0;
#pragma unroll
    for (int u = 1; u < 6; ++u) if (m >= c_blkoff[u]) img = u;
    const int bi = m - c_blkoff[img];
    const int wmrg = c_wm[img];
    const int gi = bi / wmrg;
    const int gj = bi - gi * wmrg;
    const int w  = c_w[img];
    const int kh = seg >> 1, kw = seg & 1;
    const int tok = c_tokoff[img] + 2 * gi * w + 2 * gj + kh * w + kw;
    const float4* src = (const float4*)(feat + (size_t)tok * N_DIM + d0);
    float4 v0 = src[0], v1 = src[1], v2 = src[2], v3 = src[3];
    union { __hip_bfloat162 h[8]; uint4 u4[2]; } pk;
    pk.h[0] = __float22bfloat162_rn(make_float2(v0.x, v0.y));
    pk.h[1] = __float22bfloat162_rn(make_float2(v0.z, v0.w));
    pk.h[2] = __float22bfloat162_rn(make_float2(v1.x, v1.y));
    pk.h[3] = __float22bfloat162_rn(make_float2(v1.z, v1.w));
    pk.h[4] = __float22bfloat162_rn(make_float2(v2.x, v2.y));
    pk.h[5] = __float22bfloat162_rn(make_float2(v2.z, v2.w));
    pk.h[6] = __float22bfloat162_rn(make_float2(v3.x, v3.y));
    pk.h[7] = __float22bfloat162_rn(make_float2(v3.z, v3.w));
    uint4* dst = (uint4*)(Am + (size_t)m * K_DIM + seg * 1024 + d0);
    dst[0] = pk.u4[0];
    dst[1] = pk.u4[1];
}

// ---------------------------------------------------------------------------
// Dense bf16 GEMM — the proven round-0 inner loop (128x128 tile, BK=64,
// 4 waves 2x2 of 64x64, 16x16x32 MFMA, global_load_lds width-16 staging,
// XOR-8 chunk swizzle -> conflict-free ds_read_b128), with:
//   * dense pre-merged A (no gather logic, no 4x A over-fetch)
//   * bijective XCD-chunked grid swizzle (752 = 8*94): the 8 N-tiles
//     sharing an A M-panel run adjacently on ONE XCD's L2.
// 32 KB LDS / 256 threads -> multi-block residency per CU (TLP covers the
// per-K-step drain; m114: co-resident waves capture the overlap).
// ---------------------------------------------------------------------------
__global__ __launch_bounds__(256) void gemm_bt(
    const __hip_bfloat16* __restrict__ Am,  // [M_TOT x 4096] merged bf16
    const __hip_bfloat16* __restrict__ Wp,  // [1024 x 4096] permuted bf16
    float* __restrict__ C)
{
    __shared__ __align__(16) __hip_bfloat16 lA[BM * BK]; // 16 KB
    __shared__ __align__(16) __hip_bfloat16 lB[BN * BK]; // 16 KB

    // ---- bijective XCD-chunked swizzle: 752 = 8 * 94
    const int f    = blockIdx.x;
    const int xcd  = f & 7;
    const int slot = f >> 3;                 // 0..93
    const int wgid = xcd * NWG_M + slot;     // contiguous chunk per XCD
    const int mt   = wgid >> 3;              // 0..93
    const int nt   = wgid & 7;               // 0..7 (fastest within chunk)
    const int m0 = mt * BM;
    const int n0 = nt * BN;

    const int tid  = threadIdx.x;
    const int lane = tid & 63;
    const int wave = tid >> 6;
    const int wm = (wave >> 1) * 64;
    const int wn = (wave & 1) * 64;
    const int al = lane & 15;
    const int q  = lane >> 4;
    const int al7 = al & 7;

    // ---- staging descriptors: chunk c = tid + j*256, row = c>>3,
    // LDS slot p = c&7 holds global chunk g = p ^ (row&7).
    const __hip_bfloat16* srcA[4];
    const __hip_bfloat16* srcB[4];
#pragma unroll
    for (int j = 0; j < 4; ++j) {
        const int c = tid + j * 256;
        const int row = c >> 3;
        const int g = (c & 7) ^ (row & 7);
        int gm = m0 + row; if (gm > M_TOT - 1) gm = M_TOT - 1;  // clamp tail
        srcA[j] = Am + (size_t)gm * K_DIM + g * 8;
        srcB[j] = Wp + (size_t)(n0 + row) * K_DIM + g * 8;
    }

    f32x4 acc[4][4];
#pragma unroll
    for (int i = 0; i < 4; ++i)
#pragma unroll
        for (int j = 0; j < 4; ++j)
            acc[i][j] = (f32x4){0.f, 0.f, 0.f, 0.f};

    for (int k2 = 0; k2 < K_DIM; k2 += BK) {
#pragma unroll
        for (int j = 0; j < 4; ++j)
            __builtin_amdgcn_global_load_lds(
                (const __attribute__((address_space(1))) void*)(srcA[j] + k2),
                (__attribute__((address_space(3))) void*)(lA + (tid + j * 256) * 8),
                16, 0, 0);
#pragma unroll
        for (int j = 0; j < 4; ++j)
            __builtin_amdgcn_global_load_lds(
                (const __attribute__((address_space(1))) void*)(srcB[j] + k2),
                (__attribute__((address_space(3))) void*)(lB + (tid + j * 256) * 8),
                16, 0, 0);
        __syncthreads();   // DMA complete (vmcnt drain) before reads

        bf16x8 af[4], bfr[4];
#pragma unroll
        for (int ks = 0; ks < 2; ++ks) {
#pragma unroll
            for (int mi = 0; mi < 4; ++mi) {
                const int r = wm + mi * 16 + al;
                const int p = (ks * 4 + q) ^ al7;
                af[mi] = *(const bf16x8*)(lA + r * BK + p * 8);
            }
#pragma unroll
            for (int ni = 0; ni < 4; ++ni) {
                const int r = wn + ni * 16 + al;
                const int p = (ks * 4 + q) ^ al7;
                bfr[ni] = *(const bf16x8*)(lB + r * BK + p * 8);
            }
#pragma unroll
            for (int mi = 0; mi < 4; ++mi)
#pragma unroll
                for (int ni = 0; ni < 4; ++ni)
                    acc[mi][ni] = __builtin_amdgcn_mfma_f32_16x16x32_bf16(
                        af[mi], bfr[ni], acc[mi][ni], 0, 0, 0);
        }
        __syncthreads();   // reads done before next tile's DMA lands
    }

    // C/D layout: col = lane&15, row = (lane>>4)*4 + reg
#pragma unroll
    for (int mi = 0; mi < 4; ++mi) {
        const int row = m0 + wm + mi * 16 + q * 4;
#pragma unroll
        for (int ni = 0; ni < 4; ++ni) {
            const int col = n0 + wn + ni * 16 + al;
            float* cp = C + (size_t)row * N_DIM + col;
#pragma unroll
            for (int rg = 0; rg < 4; ++rg) {
                if (row + rg < M_TOT) cp[(size_t)rg * N_DIM] = acc[mi][ni][rg];
            }
        }
    }
}

extern "C" void kernel_launch(void* const* d_in, const int* in_sizes, int n_in,
                              void* d_out, int out_size, void* d_ws, size_t ws_size,
                              hipStream_t stream)
{
    const float* feat = (const float*)d_in[0];
    const float* wgt  = (const float*)d_in[1];
    float* out = (float*)d_out;

    __hip_bfloat16* Am = (__hip_bfloat16*)d_ws;                 // 98 MB
    __hip_bfloat16* wp = (__hip_bfloat16*)((char*)d_ws +
                         (size_t)M_TOT * K_DIM * sizeof(__hip_bfloat16)); // +8 MB

    wperm_cvt<<<2048, 256, 0, stream>>>(wgt, wp);
    unfold_cvt<<<M_TOT, 256, 0, stream>>>(feat, Am);
    gemm_bt<<<NWG, 256, 0, stream>>>(Am, wp, out);
}

// Round 7
// 456.676 us; speedup vs baseline: 1.0314x; 1.0314x over previous
//
#include <hip/hip_runtime.h>
#include <hip/hip_bf16.h>
#include <stdint.h>

// Problem constants (IMAGE_SIZES is compile-time constant in the reference)
#define K_DIM 4096          // D * MERGE^2
#define N_DIM 1024          // D
#define M_TOT 11955         // total merged blocks

#define BM 128
#define BN 128
#define BK 64
#define KT_N 64             // K_DIM / BK
#define NWG_M 94            // ceil(11955/128)
#define NWG 752             // 94 * 8, divisible by 8 XCDs

// Per-image tables: h = H/14, w = W/14; wm = w/2
__constant__ int c_wm[6]     = {44, 55, 45, 55, 32, 55};
__constant__ int c_w[6]      = {88, 110, 90, 110, 64, 110};
__constant__ int c_tokoff[6] = {0, 9680, 18480, 24240, 36340, 42100};
__constant__ int c_blkoff[6] = {0, 2420, 4620, 6060, 9085, 10525};

typedef __attribute__((ext_vector_type(8))) short bf16x8;
typedef __attribute__((ext_vector_type(4))) float f32x4;

// raw workgroup barrier: NO automatic vmcnt/lgkmcnt drain (unlike
// __syncthreads), with compiler memory fences to pin ordering.
#define BARRIER() do { asm volatile("" ::: "memory"); \
                       __builtin_amdgcn_s_barrier();  \
                       asm volatile("" ::: "memory"); } while (0)
#define WAIT_VM(N) asm volatile("s_waitcnt vmcnt(" #N ")" ::: "memory")

// ---------------------------------------------------------------------------
// Weight fp32 -> bf16 with K-permutation k' = seg*1024 + d where original
// k = 4d + seg (seg = 2*kh + kw). Wp[n, seg*1024+d] = W[n, 4d+seg].
// ---------------------------------------------------------------------------
__global__ __launch_bounds__(256) void wperm_cvt(
    const float* __restrict__ src, __hip_bfloat16* __restrict__ dst)
{
    const int n = blockIdx.x >> 1;
    const int t = (blockIdx.x & 1) * 256 + threadIdx.x;   // 0..511
    const float* row = src + (size_t)n * K_DIM + t * 8;
    float4 a = *(const float4*)row;        // k = 8t..8t+3  (d = 2t)
    float4 b = *(const float4*)(row + 4);  // k = 8t+4..8t+7 (d = 2t+1)
    const float va[8] = {a.x, a.y, a.z, a.w, b.x, b.y, b.z, b.w};
    __hip_bfloat16* drow = dst + (size_t)n * K_DIM + 2 * t;
#pragma unroll
    for (int seg = 0; seg < 4; ++seg) {
        __hip_bfloat162 h = __float22bfloat162_rn(
            make_float2(va[seg], va[4 + seg]));
        *(__hip_bfloat162*)(drow + seg * 1024) = h;
    }
}

// ---------------------------------------------------------------------------
// Unfold + cvt: Am[m, seg*1024+d] = bf16(feat[tok(m,seg)*1024 + d]).
// One block per merged row: 4x 4KB contiguous reads, one 8KB contiguous
// write. After this the GEMM is a plain dense [M x 4096] @ [1024 x 4096]^T.
// ---------------------------------------------------------------------------
__global__ __launch_bounds__(256) void unfold_cvt(
    const float* __restrict__ feat, __hip_bfloat16* __restrict__ Am)
{
    const int m = blockIdx.x;            // 0..M_TOT-1
    const int t = threadIdx.x;           // 0..255
    const int seg = t >> 6;              // 0..3
    const int d0 = (t & 63) * 16;        // 0..1008
    int img = 0;
#pragma unroll
    for (int u = 1; u < 6; ++u) if (m >= c_blkoff[u]) img = u;
    const int bi = m - c_blkoff[img];
    const int wmrg = c_wm[img];
    const int gi = bi / wmrg;
    const int gj = bi - gi * wmrg;
    const int w  = c_w[img];
    const int kh = seg >> 1, kw = seg & 1;
    const int tok = c_tokoff[img] + 2 * gi * w + 2 * gj + kh * w + kw;
    const float4* src = (const float4*)(feat + (size_t)tok * N_DIM + d0);
    float4 v0 = src[0], v1 = src[1], v2 = src[2], v3 = src[3];
    union { __hip_bfloat162 h[8]; uint4 u4[2]; } pk;
    pk.h[0] = __float22bfloat162_rn(make_float2(v0.x, v0.y));
    pk.h[1] = __float22bfloat162_rn(make_float2(v0.z, v0.w));
    pk.h[2] = __float22bfloat162_rn(make_float2(v1.x, v1.y));
    pk.h[3] = __float22bfloat162_rn(make_float2(v1.z, v1.w));
    pk.h[4] = __float22bfloat162_rn(make_float2(v2.x, v2.y));
    pk.h[5] = __float22bfloat162_rn(make_float2(v2.z, v2.w));
    pk.h[6] = __float22bfloat162_rn(make_float2(v3.x, v3.y));
    pk.h[7] = __float22bfloat162_rn(make_float2(v3.z, v3.w));
    uint4* dst = (uint4*)(Am + (size_t)m * K_DIM + seg * 1024 + d0);
    dst[0] = pk.u4[0];
    dst[1] = pk.u4[1];
}

// ---------------------------------------------------------------------------
// Dense bf16 GEMM with COUNTED-VMCNT double-buffer pipeline (T4):
//   prologue: issue tiles 0,1 (8 gload_lds/thread each; 16 outstanding).
//   iter kt:  s_waitcnt vmcnt(8)   <- tile kt landed; kt+1 STAYS IN FLIGHT
//             raw barrier          (no drain -- unlike __syncthreads)
//             ds_read + 32 MFMA on buf[kt&1]
//             raw barrier          (all waves done reading buf[kt&1])
//             issue tile kt+2 into buf[kt&1]
//   last iter uses vmcnt(0) (only 8 outstanding; vmcnt(8) would be a no-op).
// The prefetch survives the barrier -- r0/r6's __syncthreads drained vmcnt
// to 0 every K-step, exposing full load latency 64x (time was invariant to
// traffic: 172 us @392 MB vs 186 us @120 MB). m218: counted-vs-drain0 +38%.
// XOR-8 chunk swizzle (slot p holds chunk g = p ^ (row&7), DMA dest linear /
// source pre-swizzled) keeps fragment ds_read_b128 conflict-free.
// 64 KB LDS -> 2 blocks/CU co-resident (TLP covers barrier dead-time, m114).
// Grid: bijective XCD-chunked swizzle (752 = 8*94), n-tile fastest in-chunk.
// ---------------------------------------------------------------------------
__global__ __launch_bounds__(256) void gemm_bt(
    const __hip_bfloat16* __restrict__ Am,  // [M_TOT x 4096] merged bf16
    const __hip_bfloat16* __restrict__ Wp,  // [1024 x 4096] permuted bf16
    float* __restrict__ C)
{
    __shared__ __align__(16) __hip_bfloat16 lA[2][BM * BK]; // 2 x 16 KB
    __shared__ __align__(16) __hip_bfloat16 lB[2][BN * BK]; // 2 x 16 KB

    // ---- bijective XCD-chunked swizzle: 752 = 8 * 94
    const int f    = blockIdx.x;
    const int xcd  = f & 7;
    const int slot = f >> 3;                 // 0..93
    const int wgid = xcd * NWG_M + slot;     // contiguous chunk per XCD
    const int mt   = wgid >> 3;              // 0..93
    const int nt   = wgid & 7;               // 0..7 (fastest within chunk)
    const int m0 = mt * BM;
    const int n0 = nt * BN;

    const int tid  = threadIdx.x;
    const int lane = tid & 63;
    const int wave = tid >> 6;
    const int wm = (wave >> 1) * 64;
    const int wn = (wave & 1) * 64;
    const int al = lane & 15;
    const int q  = lane >> 4;
    const int al7 = al & 7;

    // ---- staging descriptors: chunk c = tid + j*256, row = c>>3,
    // LDS slot p = c&7 holds global chunk g = p ^ (row&7).
    const __hip_bfloat16* srcA[4];
    const __hip_bfloat16* srcB[4];
#pragma unroll
    for (int j = 0; j < 4; ++j) {
        const int c = tid + j * 256;
        const int row = c >> 3;
        const int g = (c & 7) ^ (row & 7);
        int gm = m0 + row; if (gm > M_TOT - 1) gm = M_TOT - 1;  // clamp tail
        srcA[j] = Am + (size_t)gm * K_DIM + g * 8;
        srcB[j] = Wp + (size_t)(n0 + row) * K_DIM + g * 8;
    }

#define ISSUE_TILE(KT, BUF) do {                                              \
    const int _off = (KT) * BK;                                               \
    _Pragma("unroll")                                                         \
    for (int _j = 0; _j < 4; ++_j)                                            \
        __builtin_amdgcn_global_load_lds(                                     \
            (const __attribute__((address_space(1))) void*)(srcA[_j] + _off), \
            (__attribute__((address_space(3))) void*)(&lA[BUF][0] +           \
                (tid + _j * 256) * 8), 16, 0, 0);                             \
    _Pragma("unroll")                                                         \
    for (int _j = 0; _j < 4; ++_j)                                            \
        __builtin_amdgcn_global_load_lds(                                     \
            (const __attribute__((address_space(1))) void*)(srcB[_j] + _off), \
            (__attribute__((address_space(3))) void*)(&lB[BUF][0] +           \
                (tid + _j * 256) * 8), 16, 0, 0);                             \
} while (0)

    // ---- prologue: tiles 0 and 1 in flight (16 loads/thread outstanding)
    ISSUE_TILE(0, 0);
    ISSUE_TILE(1, 1);

    f32x4 acc[4][4];
#pragma unroll
    for (int i = 0; i < 4; ++i)
#pragma unroll
        for (int j = 0; j < 4; ++j)
            acc[i][j] = (f32x4){0.f, 0.f, 0.f, 0.f};

    for (int kt = 0; kt < KT_N; ++kt) {
        // wait ONLY for tile kt (8 oldest loads); tile kt+1 stays in flight.
        if (kt == KT_N - 1) { WAIT_VM(0); } else { WAIT_VM(8); }
        BARRIER();   // all waves' tile-kt DMA landed -> LDS readable

        const __hip_bfloat16* la = &lA[kt & 1][0];
        const __hip_bfloat16* lb = &lB[kt & 1][0];
        bf16x8 af[4], bfr[4];
#pragma unroll
        for (int ks = 0; ks < 2; ++ks) {
#pragma unroll
            for (int mi = 0; mi < 4; ++mi) {
                const int r = wm + mi * 16 + al;
                const int p = (ks * 4 + q) ^ al7;
                af[mi] = *(const bf16x8*)(la + r * BK + p * 8);
            }
#pragma unroll
            for (int ni = 0; ni < 4; ++ni) {
                const int r = wn + ni * 16 + al;
                const int p = (ks * 4 + q) ^ al7;
                bfr[ni] = *(const bf16x8*)(lb + r * BK + p * 8);
            }
#pragma unroll
            for (int mi = 0; mi < 4; ++mi)
#pragma unroll
                for (int ni = 0; ni < 4; ++ni)
                    acc[mi][ni] = __builtin_amdgcn_mfma_f32_16x16x32_bf16(
                        af[mi], bfr[ni], acc[mi][ni], 0, 0, 0);
        }

        BARRIER();   // all waves done reading buf[kt&1] -> safe to overwrite
        if (kt + 2 < KT_N) ISSUE_TILE(kt + 2, kt & 1);
    }
#undef ISSUE_TILE

    // C/D layout: col = lane&15, row = (lane>>4)*4 + reg
#pragma unroll
    for (int mi = 0; mi < 4; ++mi) {
        const int row = m0 + wm + mi * 16 + q * 4;
#pragma unroll
        for (int ni = 0; ni < 4; ++ni) {
            const int col = n0 + wn + ni * 16 + al;
            float* cp = C + (size_t)row * N_DIM + col;
#pragma unroll
            for (int rg = 0; rg < 4; ++rg) {
                if (row + rg < M_TOT) cp[(size_t)rg * N_DIM] = acc[mi][ni][rg];
            }
        }
    }
}

extern "C" void kernel_launch(void* const* d_in, const int* in_sizes, int n_in,
                              void* d_out, int out_size, void* d_ws, size_t ws_size,
                              hipStream_t stream)
{
    const float* feat = (const float*)d_in[0];
    const float* wgt  = (const float*)d_in[1];
    float* out = (float*)d_out;

    __hip_bfloat16* Am = (__hip_bfloat16*)d_ws;                 // 98 MB
    __hip_bfloat16* wp = (__hip_bfloat16*)((char*)d_ws +
                         (size_t)M_TOT * K_DIM * sizeof(__hip_bfloat16)); // +8 MB

    wperm_cvt<<<2048, 256, 0, stream>>>(wgt, wp);
    unfold_cvt<<<M_TOT, 256, 0, stream>>>(feat, Am);
    gemm_bt<<<NWG, 256, 0, stream>>>(Am, wp, out);
}